// Round 10
// baseline (6081.850 us; speedup 1.0000x reference)
//
#include <hip/hip_runtime.h>
#include <math.h>

typedef _Float16 half_t;
typedef _Float16 half8 __attribute__((ext_vector_type(8)));
typedef float f32x4 __attribute__((ext_vector_type(4)));
typedef unsigned int u32x4 __attribute__((ext_vector_type(4)));
typedef unsigned long long u64;

#define B_ 128
#define T_ 256
#define I_ 512
#define H_ 1024

#define mfma16 __builtin_amdgcn_mfma_f32_16x16x32_f16

// ---------------------------------------------------------------------------
// prep: convert x fp32 -> fp16, TRANSPOSED to [t][row][k] (per-step slab = 128KB)
__global__ void k_convert_x(const float* __restrict__ x, half_t* __restrict__ x16, int n8) {
    int i = blockIdx.x * blockDim.x + threadIdx.x;
    if (i >= n8) return;
    const float4* xv = (const float4*)x;
    float4 a = xv[2 * i], b = xv[2 * i + 1];
    half8 o;
    o[0] = (half_t)a.x; o[1] = (half_t)a.y; o[2] = (half_t)a.z; o[3] = (half_t)a.w;
    o[4] = (half_t)b.x; o[5] = (half_t)b.y; o[6] = (half_t)b.z; o[7] = (half_t)b.w;
    int e = i * 8;
    int k = e & (I_ - 1);
    int t = (e >> 9) & (T_ - 1);
    int row = e >> 17;
    ((half8*)x16)[(((size_t)t * B_ + row) * I_ + k) >> 3] = o;
}

// prep: pack W_ih|W_hh (fp32, torch gate order i,f,g,o) into fp16 MFMA
// B-fragment order. Layout: [hgroup(128)][kb(Ktot/32)][ntile(2)][lane(64)][j(8)]
__global__ void k_pack_w(const float* __restrict__ Wih, const float* __restrict__ Whh,
                         half_t* __restrict__ out, int Kx, int Ktot) {
    int idx = blockIdx.x * blockDim.x + threadIdx.x;
    int total = 4096 * Ktot;
    if (idx >= total) return;
    int j = idx & 7;
    int lane = (idx >> 3) & 63;
    int nt = (idx >> 9) & 1;
    int rest = idx >> 10;
    int nkb = Ktot >> 5;
    int kb = rest % nkb;
    int hg = rest / nkb;
    int nl = nt * 16 + (lane & 15);
    int gate = nl >> 3, hoff = nl & 7;
    int row = gate * 1024 + hg * 8 + hoff;
    int k = kb * 32 + (lane >> 4) * 8 + j;
    float v = (k < Kx) ? Wih[(size_t)row * Kx + k] : Whh[(size_t)row * 1024 + (k - Kx)];
    out[idx] = (half_t)v;
}

// prep: bias packed to [hgroup*32 + gate*8 + hoff], b_ih + b_hh summed
__global__ void k_pack_bias(const float* __restrict__ bih, const float* __restrict__ bhh,
                            float* __restrict__ out) {
    int idx = blockIdx.x * blockDim.x + threadIdx.x;
    if (idx >= 4096) return;
    int hg = idx >> 5, c = idx & 31;
    int gate = c >> 3, hoff = c & 7;
    int row = gate * 1024 + hg * 8 + hoff;
    out[idx] = bih[row] + bhh[row];
}

__global__ void k_zero(unsigned int* __restrict__ p, int n) {
    int i = blockIdx.x * blockDim.x + threadIdx.x;
    if (i < n) p[i] = 0u;
}

// ---------------------------------------------------------------------------
// 16B write-through store (single transaction, L2-bypassing, MALL-visible)
__device__ __forceinline__ void sysst128(half_t* p, half8 v) {
    asm volatile("global_store_dwordx4 %0, %1, off sc0 sc1"
                 :: "v"(p), "v"(v) : "memory");
}

// ---------------------------------------------------------------------------
// Persistent, layer-pipelined. 256 blocks x 1024 thr (16 waves), 1 block/CU.
// Block = (rgB in {0,1}, cg in [0,128)): rows [64*rgB, +64), hgroup cg
// (32 gate-cols), BOTH layers. Waves 0-7: layer0 K-slices; waves 8-15: layer1.
// Epoch e: L0 computes step e (e<256), L1 computes step e-1 (e>=1) -- both
// depend only on epoch e-1 publications => 257 serial epochs (was 512).
// gacc = [layer][8 ks][32 rows][32 cols] (64KB), two row-passes per epoch.
// Flags: fl[rgB*512 + {cg | 128+cg}] = epochs completed per (layer, cg).
__launch_bounds__(1024, 4)
__global__ void lstm_persist(const half_t* __restrict__ x16T,
                             half_t* h1seq, half_t* h2seq,
                             const half_t* __restrict__ wp0, const half_t* __restrict__ wp1,
                             const float* __restrict__ bias0, const float* __restrict__ bias1,
                             unsigned* __restrict__ flags)
{
    __shared__ float gacc[2 * 8 * 32 * 32];   // 64 KB
    __shared__ half_t hstg[2][512];           // 2 KB
    const int bid = blockIdx.x;
    const int rgB = bid & 1;
    const int cg  = bid >> 1;
    const int hg  = cg;
    const int r0  = rgB * 64;
    const int tid = threadIdx.x;
    const int w   = tid >> 6;
    const int lane = tid & 63;
    const int q = lane >> 4, ml = lane & 15;
    unsigned* fl = flags + rgB * 512;   // [0..127]=L0 flags, [128..255]=L1 flags

    if (w < 8) {
        // =================== LAYER-0 WAVES (+ reduce + publish) ===================
        const int ks = w;
        half8 B0[6][2];   // kbs: {2ks,2ks+1} (x-part), {16+4ks..+3} (h-part)
        {
            const half8* W = (const half8*)wp0;
            size_t base = (size_t)hg * 48 * 128 + lane;
#pragma unroll
            for (int i = 0; i < 6; ++i) {
                int kb = (i < 2) ? (2 * ks + i) : (16 + 4 * ks + (i - 2));
                B0[i][0] = W[base + (size_t)kb * 128];
                B0[i][1] = W[base + (size_t)kb * 128 + 64];
            }
#pragma unroll
            for (int i = 0; i < 6; ++i)
                asm volatile("" : "+v"(B0[i][0]), "+v"(B0[i][1]));
        }
        // reduce/elementwise identity: tid<512 -> (lay, row, hoff); two row-passes
        const int lay = tid >> 8;
        const int idx = tid & 255;
        const int row = idx >> 3, hoff = idx & 7;
        const float* bp = lay ? bias1 : bias0;
        const float bi = bp[hg * 32 + hoff],      bf = bp[hg * 32 + 8 + hoff];
        const float bg = bp[hg * 32 + 16 + hoff], bo = bp[hg * 32 + 24 + hoff];
        float cA = 0.f, cB = 0.f;   // c-state for (lay,row) and (lay,row+32)
        unsigned* myF0 = fl + cg;
        unsigned* myF1 = fl + 128 + cg;

        for (int e = 0; e <= T_; ++e) {
            if (e > 0) {
                if (tid < 64) {   // wave0 polls both layers' producer flags
                    unsigned tgt = (lane < 32) ? (unsigned)e : (unsigned)(e - 1);
                    const unsigned* p = (lane < 32) ? (fl + lane * 4)
                                                    : (fl + 128 + (lane - 32) * 4);
                    int gd = 0;
                    for (;;) {
                        u32x4 v;
                        asm volatile("global_load_dwordx4 %0, %1, off sc0 sc1\n\t"
                                     "s_waitcnt vmcnt(0)"
                                     : "=v"(v) : "v"(p) : "memory");
                        if (__all((int)(v[0] >= tgt && v[1] >= tgt &&
                                        v[2] >= tgt && v[3] >= tgt))) break;
                        __builtin_amdgcn_s_sleep(2);
                        if (++gd > (1 << 15)) break;  // failsafe: visible fail
                    }
                }
                __syncthreads();   // barrier 1
                asm volatile("" ::: "memory");
            }
            f32x4 acc[4][2];
            if (e < T_) {
#pragma unroll
                for (int rt = 0; rt < 4; ++rt) { acc[rt][0] = (f32x4)0.f; acc[rt][1] = (f32x4)0.f; }
#pragma unroll
                for (int i = 0; i < 6; ++i) {
                    int kb = (i < 2) ? (2 * ks + i) : (16 + 4 * ks + (i - 2));
                    int kg = kb * 32 + q * 8;
#pragma unroll
                    for (int rt = 0; rt < 4; ++rt) {
                        int grow = r0 + rt * 16 + ml;
                        const half_t* ap = (i < 2)
                            ? x16T + ((size_t)e * B_ + grow) * I_ + kg
                            : h1seq + ((size_t)e * B_ + grow) * H_ + (kg - I_);
                        half8 a = *(const half8*)ap;
                        acc[rt][0] = mfma16(a, B0[i][0], acc[rt][0], 0, 0, 0);
                        acc[rt][1] = mfma16(a, B0[i][1], acc[rt][1], 0, 0, 0);
                    }
                }
                // pass-A gacc write: rows 0..31 (rt 0,1)
#pragma unroll
                for (int rt = 0; rt < 2; ++rt)
#pragma unroll
                    for (int ct = 0; ct < 2; ++ct)
#pragma unroll
                        for (int r = 0; r < 4; ++r) {
                            int rl = rt * 16 + q * 4 + r;
                            int cl = ct * 16 + ml;
                            gacc[ks * 1024 + rl * 32 + (cl ^ ((rl & 7) << 2))] = acc[rt][ct][r];
                        }
            }
            __syncthreads();   // barrier 2
            bool valid = (lay == 0) ? (e < T_) : (e >= 1);
            if (tid < 512 && valid) {   // reduce+elementwise rows 0..31
                const float* gb = gacc + lay * 8192;
                int swz = (row & 7) << 2;
                float pi = 0.f, pf = 0.f, pg = 0.f, po = 0.f;
#pragma unroll
                for (int z = 0; z < 8; ++z) {
                    const float* g = gb + z * 1024 + row * 32;
                    pi += g[(0 + hoff) ^ swz];
                    pf += g[(8 + hoff) ^ swz];
                    pg += g[(16 + hoff) ^ swz];
                    po += g[(24 + hoff) ^ swz];
                }
                pi += bi; pf += bf; pg += bg; po += bo;
                float si = 1.f / (1.f + __expf(-pi));
                float sf = 1.f / (1.f + __expf(-pf));
                float so = 1.f / (1.f + __expf(-po));
                float tg = 1.f - 2.f / (__expf(2.f * pg) + 1.f);
                cA = sf * cA + si * tg;
                float th = 1.f - 2.f / (__expf(2.f * cA) + 1.f);
                hstg[lay][row * 8 + hoff] = (half_t)(so * th);
            }
            __syncthreads();   // barrier 3
            if (e < T_) {       // pass-B gacc write: rows 32..63 (rt 2,3)
#pragma unroll
                for (int rt = 2; rt < 4; ++rt)
#pragma unroll
                    for (int ct = 0; ct < 2; ++ct)
#pragma unroll
                        for (int r = 0; r < 4; ++r) {
                            int rl = (rt - 2) * 16 + q * 4 + r;
                            int cl = ct * 16 + ml;
                            gacc[ks * 1024 + rl * 32 + (cl ^ ((rl & 7) << 2))] = acc[rt][ct][r];
                        }
            }
            __syncthreads();   // barrier 4
            if (tid < 512 && valid) {   // reduce+elementwise rows 32..63
                const float* gb = gacc + lay * 8192;
                int swz = (row & 7) << 2;
                float pi = 0.f, pf = 0.f, pg = 0.f, po = 0.f;
#pragma unroll
                for (int z = 0; z < 8; ++z) {
                    const float* g = gb + z * 1024 + row * 32;
                    pi += g[(0 + hoff) ^ swz];
                    pf += g[(8 + hoff) ^ swz];
                    pg += g[(16 + hoff) ^ swz];
                    po += g[(24 + hoff) ^ swz];
                }
                pi += bi; pf += bf; pg += bg; po += bo;
                float si = 1.f / (1.f + __expf(-pi));
                float sf = 1.f / (1.f + __expf(-pf));
                float so = 1.f / (1.f + __expf(-po));
                float tg = 1.f - 2.f / (__expf(2.f * pg) + 1.f);
                cB = sf * cB + si * tg;
                float th = 1.f - 2.f / (__expf(2.f * cB) + 1.f);
                hstg[lay][(row + 32) * 8 + hoff] = (half_t)(so * th);
            }
            __syncthreads();   // barrier 5
            // publish: wave0 only (64 rows x 2 layers, 16B each), then flags
            if (tid < 64) {
                if (e < T_)
                    sysst128(h1seq + ((size_t)(e + 1) * B_ + r0 + lane) * H_ + hg * 8,
                             *(const half8*)&hstg[0][lane * 8]);
                if (e >= 1)
                    sysst128(h2seq + ((size_t)e * B_ + r0 + lane) * H_ + hg * 8,
                             *(const half8*)&hstg[1][lane * 8]);
            }
            if (tid == 0) {
                asm volatile("s_waitcnt vmcnt(0)" ::: "memory");  // drain this wave's stores
                if (e < T_) __hip_atomic_store(myF0, (unsigned)(e + 1),
                                               __ATOMIC_RELAXED, __HIP_MEMORY_SCOPE_SYSTEM);
                if (e >= 1) __hip_atomic_store(myF1, (unsigned)e,
                                               __ATOMIC_RELAXED, __HIP_MEMORY_SCOPE_SYSTEM);
            }
            // no trailing barrier: wave0 rejoins at next epoch's barrier 1
        }
    } else {
        // =================== LAYER-1 WAVES (MFMA only) ===================
        const int ks = w - 8;
        half8 B1[8][2];   // kbs: {4ks..+3} (h1-part), {32+4ks..+3} (h2-part)
        {
            const half8* W = (const half8*)wp1;
            size_t base = (size_t)hg * 64 * 128 + lane;
#pragma unroll
            for (int i = 0; i < 8; ++i) {
                int kb = (i < 4) ? (4 * ks + i) : (32 + 4 * ks + (i - 4));
                B1[i][0] = W[base + (size_t)kb * 128];
                B1[i][1] = W[base + (size_t)kb * 128 + 64];
            }
#pragma unroll
            for (int i = 0; i < 8; ++i)
                asm volatile("" : "+v"(B1[i][0]), "+v"(B1[i][1]));
        }
        for (int e = 0; e <= T_; ++e) {
            if (e > 0) { __syncthreads(); asm volatile("" ::: "memory"); }  // barrier 1
            f32x4 acc[4][2];
            if (e >= 1) {
#pragma unroll
                for (int rt = 0; rt < 4; ++rt) { acc[rt][0] = (f32x4)0.f; acc[rt][1] = (f32x4)0.f; }
#pragma unroll
                for (int i = 0; i < 8; ++i) {
                    int kb = (i < 4) ? (4 * ks + i) : (32 + 4 * ks + (i - 4));
                    int ko = kb * 32 + q * 8;
#pragma unroll
                    for (int rt = 0; rt < 4; ++rt) {
                        int grow = r0 + rt * 16 + ml;
                        const half_t* ap = (i < 4)
                            ? h1seq + ((size_t)e * B_ + grow) * H_ + ko
                            : h2seq + ((size_t)(e - 1) * B_ + grow) * H_ + (ko - 1024);
                        half8 a = *(const half8*)ap;
                        acc[rt][0] = mfma16(a, B1[i][0], acc[rt][0], 0, 0, 0);
                        acc[rt][1] = mfma16(a, B1[i][1], acc[rt][1], 0, 0, 0);
                    }
                }
#pragma unroll
                for (int rt = 0; rt < 2; ++rt)   // pass-A: rows 0..31
#pragma unroll
                    for (int ct = 0; ct < 2; ++ct)
#pragma unroll
                        for (int r = 0; r < 4; ++r) {
                            int rl = rt * 16 + q * 4 + r;
                            int cl = ct * 16 + ml;
                            gacc[8192 + ks * 1024 + rl * 32 + (cl ^ ((rl & 7) << 2))] = acc[rt][ct][r];
                        }
            }
            __syncthreads();   // barrier 2
            __syncthreads();   // barrier 3
            if (e >= 1) {
#pragma unroll
                for (int rt = 2; rt < 4; ++rt)   // pass-B: rows 32..63
#pragma unroll
                    for (int ct = 0; ct < 2; ++ct)
#pragma unroll
                        for (int r = 0; r < 4; ++r) {
                            int rl = (rt - 2) * 16 + q * 4 + r;
                            int cl = ct * 16 + ml;
                            gacc[8192 + ks * 1024 + rl * 32 + (cl ^ ((rl & 7) << 2))] = acc[rt][ct][r];
                        }
            }
            __syncthreads();   // barrier 4
            __syncthreads();   // barrier 5
        }
    }
}

// final FC: out[m] = sum_k h[m][k] * Wfc[k] + bfc  (NC=1)
__global__ void k_fc(const half_t* __restrict__ h, const float* __restrict__ Wfc,
                     const float* __restrict__ bfc, float* __restrict__ out) {
    int m = blockIdx.x, lane = threadIdx.x;
    float s = 0.f;
    for (int k = lane; k < H_; k += 64) s += (float)h[m * H_ + k] * Wfc[k];
#pragma unroll
    for (int o = 32; o; o >>= 1) s += __shfl_down(s, o, 64);
    if (lane == 0) out[m] = s + bfc[0];
}

// ---------------------------------------------------------------------------
extern "C" void kernel_launch(void* const* d_in, const int* in_sizes, int n_in,
                              void* d_out, int out_size, void* d_ws, size_t ws_size,
                              hipStream_t stream) {
    const float* x    = (const float*)d_in[0];
    const float* Wih0 = (const float*)d_in[1];
    const float* Whh0 = (const float*)d_in[2];
    const float* bih0 = (const float*)d_in[3];
    const float* bhh0 = (const float*)d_in[4];
    const float* Wih1 = (const float*)d_in[5];
    const float* Whh1 = (const float*)d_in[6];
    const float* bih1 = (const float*)d_in[7];
    const float* bhh1 = (const float*)d_in[8];
    const float* Wfc  = (const float*)d_in[9];
    const float* bfc  = (const float*)d_in[10];
    float* out = (float*)d_out;

    char* ws = (char*)d_ws;
    size_t off = 0;
    auto carve = [&](size_t bytes) { void* p = ws + off; off += (bytes + 255) & ~(size_t)255; return p; };
    half_t* x16T   = (half_t*)carve((size_t)B_ * T_ * I_ * 2);              // 33.5 MB [t][B][512]
    half_t* h1seq  = (half_t*)carve((size_t)(T_ + 1) * B_ * H_ * 2);        // 67.4 MB [t][B][H]
    half_t* h2seq  = (half_t*)carve((size_t)(T_ + 1) * B_ * H_ * 2);        // 67.4 MB [t][B][H]
    half_t* wp0    = (half_t*)carve((size_t)4096 * 1536 * 2);               // 12.6 MB
    half_t* wp1    = (half_t*)carve((size_t)4096 * 2048 * 2);               // 16.8 MB
    float*  bias0  = (float*)carve(4096 * 4);
    float*  bias1  = (float*)carve(4096 * 4);
    unsigned* flags = (unsigned*)carve(1024 * 4);                           // [rgB][2][128] padded
    if (off > ws_size) return;  // ~198 MB needed: visible failure if ws too small

    // prep
    k_convert_x<<<(B_ * T_ * I_ / 8 + 255) / 256, 256, 0, stream>>>(x, x16T, B_ * T_ * I_ / 8);
    k_pack_w<<<(4096 * 1536 + 255) / 256, 256, 0, stream>>>(Wih0, Whh0, wp0, 512, 1536);
    k_pack_w<<<(4096 * 2048 + 255) / 256, 256, 0, stream>>>(Wih1, Whh1, wp1, 1024, 2048);
    k_pack_bias<<<16, 256, 0, stream>>>(bih0, bhh0, bias0);
    k_pack_bias<<<16, 256, 0, stream>>>(bih1, bhh1, bias1);
    // per-launch zeroing (bench replays): h1seq[0], h2seq[0], flags
    k_zero<<<(B_ * H_ / 2 + 255) / 256, 256, 0, stream>>>((unsigned int*)h1seq, B_ * H_ / 2);
    k_zero<<<(B_ * H_ / 2 + 255) / 256, 256, 0, stream>>>((unsigned int*)h2seq, B_ * H_ / 2);
    k_zero<<<4, 256, 0, stream>>>(flags, 1024);

    // persistent, layer-pipelined (257 epochs), weights pinned in registers
    lstm_persist<<<dim3(256), dim3(1024), 0, stream>>>(
        x16T, h1seq, h2seq, wp0, wp1, bias0, bias1, flags);

    // h2seq[256] = L1 output at t=255
    k_fc<<<128, 64, 0, stream>>>(h2seq + (size_t)T_ * B_ * H_, Wfc, bfc, out);
}